// Round 11
// baseline (54391.620 us; speedup 1.0000x reference)
//
#include <hip/hip_runtime.h>

// Echo-state network recurrence on MI355X (gfx950).
// Round-23: FLAG-PIPELINED QUARTER EXCHANGE. r22 (LDS placement force)
// was the first real win: 47.9 -> 42.1ms, collision-free placement proven
// (LDS_Block_Size=98304 bound). Remaining critical path per step:
// own poll -> stage -> __syncthreads -> read 4 quarters -> 64 pk-FMA ->
// fold -> publish. The barrier (a) serializes ALL FMA behind the SLOWEST
// of 4 independent quarter-polls, (b) forces a vmcnt/lgkmcnt full drain.
// Fix: per-quarter generation-tagged LDS flags. Producer: ds_write data,
// lgkmcnt(0), ds_write flag=t. Consumer: spin flag, read quarter,
// immediately run its 16 pk-FMAs. Quarters processed in fixed order 0..3
// -> summation order bit-identical to r22 (pairs jj ascending). Own
// quarter used straight from poll registers. Flags mod-256 generation
// tagged + parity double-buffered + 0xAA-poisoned (no reset needed);
// LDS buffer reuse protected by lockstep gating (producer can't reach
// t+2 before every wave finishes t -- same argument as global buffers).
// Barrier kept only in the cold final-readout path.

#define HH    1024
#define TT    50000
#define WASH  200
#define NBROLE 32   // block role b owns rows [32b, 32b+32); wave ww rows [32b+8ww, +8)
#define NBLK  512
#define NT    256
#define SPIN_CAP (1u << 20)
#define LDSPAD 98304   // 96 KiB total LDS -> 1 block/CU (LDS pool 160 KiB)

typedef unsigned int u32;
typedef u32 u32x4 __attribute__((ext_vector_type(4)));
typedef float f32x4 __attribute__((ext_vector_type(4)));
typedef float f32x2 __attribute__((ext_vector_type(2)));

__device__ __forceinline__ float fast_tanh(float x) {
  // tanh(x) = 1 - 2/(exp2(2x*log2e)+1); safe at +/-inf.
  float e = __builtin_amdgcn_exp2f(x * 2.8853900817779268f);
  return fmaf(-2.0f, __builtin_amdgcn_rcpf(e + 1.0f), 1.0f);
}

template <int CTRL>
__device__ __forceinline__ float dpp_movf(float x) {
  return __int_as_float(__builtin_amdgcn_update_dpp(
      0, __float_as_int(x), CTRL, 0xF, 0xF, true));
}
__device__ __forceinline__ float swz_xor16(float x) {
  return __int_as_float(__builtin_amdgcn_ds_swizzle(__float_as_int(x), 0x401F));
}

#define YREDUCE()                                                         \
  { y += __shfl_xor(y, 32);                                               \
    y += swz_xor16(y);                                                    \
    y += dpp_movf<0x128>(y);   /* row_ror:8   */                          \
    y += dpp_movf<0x141>(y);   /* half mirror */                          \
    y += dpp_movf<0x1B>(y);    /* quad reverse*/                          \
    y += dpp_movf<0xB1>(y); }  /* quad xor1   */

// single 16B poll load: own quarter only (lane l -> cols 256*ww + 4l .. +3)
#define POLL_ISSUE1(b)                                                    \
  asm volatile("global_load_dwordx4 %0, %1, off sc1" : "=v"(p) : "v"(b))
#define POLL_WAIT1()                                                      \
  asm volatile("s_waitcnt vmcnt(0)" : "+v"(p))

// FULL 4-dword tag check -- load-bearing (partial-commit visibility of
// coalesced wave stores means every dword's tag matters).
#define TAGBAD(q) ((((q.x ^ want) | (q.y ^ want) | (q.z ^ want) | (q.w ^ want)) & 0xFFu))

// unpack one 16B chunk into two f32x2 value pairs (pair b2, b2+1)
#define UNPACK2(q, b2)                                                    \
  { xv2[b2+0] = (f32x2){__uint_as_float(q.x & 0xFFFFFF00u),               \
                        __uint_as_float(q.y & 0xFFFFFF00u)};              \
    xv2[b2+1] = (f32x2){__uint_as_float(q.z & 0xFFFFFF00u),               \
                        __uint_as_float(q.w & 0xFFFFFF00u)}; }

// --- named weight registers: row r, pairs 0..7 (cols 256*(p>>1)+4l+{2(p&1),+1})
#define DECLW(r) f32x2 W##r##0, W##r##1, W##r##2, W##r##3,                \
                      W##r##4, W##r##5, W##r##6, W##r##7

#define LOADW(r) do {                                                     \
  const float* wp = w_res + (size_t)(32 * b + 8 * ww + r) * HH + 4 * l;   \
  f32x4 va = *(const f32x4*)(wp);                                         \
  f32x4 vb = *(const f32x4*)(wp + 256);                                   \
  f32x4 vc = *(const f32x4*)(wp + 512);                                   \
  f32x4 vd = *(const f32x4*)(wp + 768);                                   \
  W##r##0 = (f32x2){va.x, va.y}; W##r##1 = (f32x2){va.z, va.w};           \
  W##r##2 = (f32x2){vb.x, vb.y}; W##r##3 = (f32x2){vb.z, vb.w};           \
  W##r##4 = (f32x2){vc.x, vc.y}; W##r##5 = (f32x2){vc.z, vc.w};           \
  W##r##6 = (f32x2){vd.x, vd.y}; W##r##7 = (f32x2){vd.z, vd.w};           \
} while (0)

// one quarter's FMAs: pairs pA=2q, pB=2q+1, rows 0..7.
// Per-acc order across quarters 0..3 is jj=0,1,...,7 ascending ==
// bit-identical to r22's FMAR sequence.
#define FMAQ(r, pA, pB)                                                   \
  acc2[r] = __builtin_elementwise_fma(W##r##pA, xv2[pA], acc2[r]);        \
  acc2[r] = __builtin_elementwise_fma(W##r##pB, xv2[pB], acc2[r]);
#define FMAQALL(pA, pB)                                                   \
  FMAQ(0, pA, pB) FMAQ(1, pA, pB) FMAQ(2, pA, pB) FMAQ(3, pA, pB)         \
  FMAQ(4, pA, pB) FMAQ(5, pA, pB) FMAQ(6, pA, pB) FMAQ(7, pA, pB)

// process quarter q: own quarter from poll regs; others flag-gated LDS.
#define QUARTER(q, pA, pB) do {                                           \
  u32x4 cq;                                                               \
  if (q == ww) { cq = p; }                                                \
  else {                                                                  \
    u32 g = 0;                                                            \
    while (vflg[(h << 2) | q] != want) { if (++g > SPIN_CAP) break; }     \
    asm volatile("" ::: "memory");                                        \
    cq = *(const u32x4*)(&lds_x[h][256 * q + 4 * l]);                     \
  }                                                                       \
  UNPACK2(cq, 2 * q);                                                     \
  FMAQALL(pA, pB);                                                        \
} while (0)

__global__ __launch_bounds__(NT, 1) void esn_kernel(
    const float* __restrict__ u,
    const float* __restrict__ w_in,
    const float* __restrict__ w_res,
    const float* __restrict__ w_out,
    const int*   __restrict__ mask,
    float*       __restrict__ out,
    char*        __restrict__ ws)
{
  const int tid = threadIdx.x;
  const int l  = tid & 63;     // lane within wave
  const int ww = tid >> 6;     // wave id within block (0..3) = quarter owner

  // --- team formation: XCD 0 only, first 32 claimant BLOCKS persist ---
  u32 xcc;
  asm("s_getreg_b32 %0, hwreg(HW_REG_XCC_ID)" : "=s"(xcc));
  if (xcc != 0) return;        // uniform per block (block lives on one CU)

  // PLACEMENT FORCE (r22-proven): 96 KiB static LDS -> 1 block/CU ->
  // the 32 claim winners sit on 32 distinct CUs.
  __shared__ __align__(16) char lds_all[LDSPAD];
  float* lds_c = (float*)lds_all;                        // 4 KB coeffs
  u32 (*lds_x)[HH] = (u32 (*)[HH])(lds_all + 4096);      // 2x4 KB state
  volatile u32* vflg = (volatile u32*)(lds_all + 4096 + 8192);  // 2x4 flags
  int* slot_p = (int*)(lds_all + 4096 + 8192 + 32);

  if (tid == 0) *slot_p = atomicAdd((int*)ws, 1);  // ws[0..63] zeroed each launch
  if (tid < 8) vflg[tid] = 0xAAAAAAAAu;            // flag poison (!= any gen)
  // init readout coeffs while the claim settles
  for (int h = tid; h < HH; h += NT) lds_c[mask[h]] = w_out[h];
  __syncthreads();
  const int b = *slot_p;
  if (b >= NBROLE) return;

  u32* xb0 = (u32*)(ws + 4096);        // parity-0 packed buffer (4 KB)
  u32* xb1 = xb0 + HH;                 // parity-1 packed buffer (4 KB)

  // weights: 8 rows x 8 col-pairs per lane (rows 32b+8ww .. +8)
  DECLW(0); DECLW(1); DECLW(2); DECLW(3);
  DECLW(4); DECLW(5); DECLW(6); DECLW(7);
  LOADW(0); LOADW(1); LOADW(2); LOADW(3);
  LOADW(4); LOADW(5); LOADW(6); LOADW(7);

  const float win = w_in[32 * b + 8 * ww + (l >> 3)];

  f32x2 cr2[8];                        // readout coeffs, same col map
#pragma unroll
  for (int k = 0; k < 4; ++k) {
    f32x4 v = *(const f32x4*)(lds_c + 256 * k + 4 * l);
    cr2[2*k+0] = (f32x2){v.x, v.y};
    cr2[2*k+1] = (f32x2){v.z, v.w};
  }

  // own-quarter poll pointers: wave ww covers cols [256ww, 256ww+256)
  const u32* pS0 = xb0 + 256 * ww + 4 * l;
  const u32* pS1 = xb1 + 256 * ww + 4 * l;
  // publish pointers: lane (l&7)==0 stores row 32b+8ww+(l>>3)
  const int drow = 32 * b + 8 * ww + (l >> 3);
  u32* d0 = xb0 + drow;
  u32* d1 = xb1 + drow;
  // LDS staging address (own quarter)
  const int stg = 256 * ww + 4 * l;

  const int role = (b << 2) | ww;      // 0..127, readout rotation
  u32x4 p;
  const int lb32 = l & 32, lb16 = l & 16, lb8 = l & 8;
  int dead = 0;

  for (int t = 0; t < TT; ++t) {
    const int pa = t & 1;
    const float u_t = u[t];
    f32x2 acc2[8];
#pragma unroll
    for (int i = 0; i < 8; ++i) acc2[i] = (f32x2){0.f, 0.f};
    f32x2 xv2[8];
    const bool doRead = ((t & 127) == role) && (t > 0);

    if (t > 0) {
      const int h = pa ^ 1;            // source parity = (t-1)&1
      const u32 want = (u32)t & 0xFFu; // generation of x_{t-1}
      if (!dead) {
        // delayed first poll: publish->ready >= store-commit + RTT;
        // ~128cyc sleep is hidden slack that kills the guaranteed-failed
        // first round.
        __builtin_amdgcn_s_sleep(2);
        const u32* src = h ? pS1 : pS0;
        u32 guard = 0;
        for (;;) {
          POLL_ISSUE1(src);
          POLL_WAIT1();
          if (!TAGBAD(p)) break;
          if (++guard > SPIN_CAP) { dead = 1; break; }
        }
      }
      // stage own quarter; complete before setting the flag (lgkmcnt(0));
      // generation-tagged flag replaces __syncthreads.
      *(u32x4*)(&lds_x[h][stg]) = p;
      asm volatile("s_waitcnt lgkmcnt(0)" ::: "memory");
      vflg[(h << 2) | ww] = want;
      // process quarters in fixed order 0..3: FMA on arrived quarters
      // overlaps the spin for late ones; own quarter straight from regs.
      QUARTER(0, 0, 1);
      QUARTER(1, 2, 3);
      QUARTER(2, 4, 5);
      QUARTER(3, 6, 7);
    }

    // horizontal pair-sum, then fold 64 lanes x 8 accs -> row (l>>3) sum
    // on lanes with (l&7)==0
    const float a0 = acc2[0].x + acc2[0].y, a1 = acc2[1].x + acc2[1].y;
    const float a2 = acc2[2].x + acc2[2].y, a3 = acc2[3].x + acc2[3].y;
    const float a4 = acc2[4].x + acc2[4].y, a5 = acc2[5].x + acc2[5].y;
    const float a6 = acc2[6].x + acc2[6].y, a7 = acc2[7].x + acc2[7].y;
    float t0 = (lb32 ? a4 : a0) + __shfl_xor(lb32 ? a0 : a4, 32);
    float t1 = (lb32 ? a5 : a1) + __shfl_xor(lb32 ? a1 : a5, 32);
    float t2 = (lb32 ? a6 : a2) + __shfl_xor(lb32 ? a2 : a6, 32);
    float t3 = (lb32 ? a7 : a3) + __shfl_xor(lb32 ? a3 : a7, 32);
    float s0 = (lb16 ? t2 : t0) + swz_xor16(lb16 ? t0 : t2);
    float s1 = (lb16 ? t3 : t1) + swz_xor16(lb16 ? t1 : t3);
    float r0 = (lb8 ? s1 : s0) + dpp_movf<0x128>(lb8 ? s0 : s1);
    r0 += dpp_movf<0x141>(r0);
    r0 += dpp_movf<0x1B>(r0);
    r0 += dpp_movf<0xB1>(r0);

    float x_new = fast_tanh(fmaf(win, u_t, r0));
    // pack: RN-round mantissa to 15 bits, fuse generation tag (t+1)&0xFF
    u32 packed = ((__float_as_uint(x_new) + 0x80u) & 0xFFFFFF00u)
               | ((u32)(t + 1) & 0xFFu);
    if ((l & 7) == 0) {
      u32* dst = pa ? d1 : d0;          // x_t -> buf[t&1]
      // PLAIN store: write-through L1 -> dirty in XCD0's shared L2
      // (r9-proven; r16 proved atomics force the exchange out of L2).
      asm volatile("global_store_dword %0, %1, off" :: "v"(dst), "v"(packed));
    }

    // readout y_{t-1} from this step's unpacked values (off critical path)
    if (doRead) {
      f32x2 y2 = (f32x2){0.f, 0.f};
#pragma unroll
      for (int jj = 0; jj < 8; ++jj)
        y2 = __builtin_elementwise_fma(cr2[jj], xv2[jj], y2);
      float y = y2.x + y2.y;
      YREDUCE();
      if (l == 0 && t - 1 >= WASH) out[t - 1 - WASH] = y;
    }
  }

  // final readout: x_{TT-1} (tag TT) in buf[1]; block 0 does one more
  // exchange (cold path -- plain barrier is fine here).
  if (b == 0) {
    const u32 want = (u32)TT & 0xFFu;
    u32 guard = 0;
    for (;;) {
      POLL_ISSUE1(pS1);
      POLL_WAIT1();
      if (!TAGBAD(p)) break;
      if (++guard > SPIN_CAP) break;
    }
    *(u32x4*)(&lds_x[1][stg]) = p;
    __syncthreads();
    if (ww == 0) {
      f32x2 xv2[8];
      u32x4 c0 = *(const u32x4*)(&lds_x[1][  0 + 4 * l]);
      u32x4 c1 = *(const u32x4*)(&lds_x[1][256 + 4 * l]);
      u32x4 c2 = *(const u32x4*)(&lds_x[1][512 + 4 * l]);
      u32x4 c3 = *(const u32x4*)(&lds_x[1][768 + 4 * l]);
      UNPACK2(c0, 0); UNPACK2(c1, 2); UNPACK2(c2, 4); UNPACK2(c3, 6);
      f32x2 y2 = (f32x2){0.f, 0.f};
#pragma unroll
      for (int jj = 0; jj < 8; ++jj)
        y2 = __builtin_elementwise_fma(cr2[jj], xv2[jj], y2);
      float y = y2.x + y2.y;
      YREDUCE();
      if (l == 0) out[TT - 1 - WASH] = y;
    }
  }
}

extern "C" void kernel_launch(void* const* d_in, const int* in_sizes, int n_in,
                              void* d_out, int out_size, void* d_ws, size_t ws_size,
                              hipStream_t stream) {
  const float* u     = (const float*)d_in[0];
  const float* w_in  = (const float*)d_in[1];
  const float* w_res = (const float*)d_in[2];
  const float* w_out = (const float*)d_in[3];
  const int*   mask  = (const int*)d_in[4];
  float* out = (float*)d_out;

  // zero the block-claim counter; packed buffers rely on 0xAA poison
  // (tag byte 0xAA only ever compared against want in {1,2})
  hipMemsetAsync(d_ws, 0, 64, stream);

  esn_kernel<<<NBLK, NT, 0, stream>>>(u, w_in, w_res, w_out, mask, out,
                                      (char*)d_ws);
}

// Round 12
// 42882.123 us; speedup vs baseline: 1.2684x; 1.2684x over previous
//
#include <hip/hip_runtime.h>

// Echo-state network recurrence on MI355X (gfx950).
// Round-24: r22 skeleton + ROLLING POLL (clean retest). r23 (LDS flag
// pipelining) regressed 42.1->54.4ms: the volatile spin gated each
// quarter's ds_read serially, destroying the barrier-batched overlap of
// the 4 ds_read_b128 latencies. LEDGER: barrier > per-quarter flags
// because it preserves bulk LDS issue. Reverted.
// This round: the ~1000cyc/step residue matches 3-4 failed serial poll
// rounds x ~225cyc RTT quantization. r17 tested rolling polls but BEFORE
// the placement force -- bimodal collision noise voided that verdict.
// Clean test now: keep 4 same-address 16B sc1 loads in flight, wait
// vmcnt(3) (oldest only), check, reissue that slot -> detection
// granularity ~35-70cyc instead of ~225. Safety: vmcnt retires in issue
// order (pending publish store only makes vmcnt(3) conservative);
// __all-uniform break; re-reads safe (slot can't be overwritten before
// gen t+2; no producer reaches t+2 before we publish t); vmcnt(0) drain
// after staging, before the barrier. Datapath bit-identical to r22.

#define HH    1024
#define TT    50000
#define WASH  200
#define NBROLE 32   // block role b owns rows [32b, 32b+32); wave ww rows [32b+8ww, +8)
#define NBLK  512
#define NT    256
#define SPIN_CAP (1u << 20)
#define LDSPAD 98304   // 96 KiB total LDS -> 1 block/CU (LDS pool 160 KiB)

typedef unsigned int u32;
typedef u32 u32x4 __attribute__((ext_vector_type(4)));
typedef float f32x4 __attribute__((ext_vector_type(4)));
typedef float f32x2 __attribute__((ext_vector_type(2)));

__device__ __forceinline__ float fast_tanh(float x) {
  // tanh(x) = 1 - 2/(exp2(2x*log2e)+1); safe at +/-inf.
  float e = __builtin_amdgcn_exp2f(x * 2.8853900817779268f);
  return fmaf(-2.0f, __builtin_amdgcn_rcpf(e + 1.0f), 1.0f);
}

template <int CTRL>
__device__ __forceinline__ float dpp_movf(float x) {
  return __int_as_float(__builtin_amdgcn_update_dpp(
      0, __float_as_int(x), CTRL, 0xF, 0xF, true));
}
__device__ __forceinline__ float swz_xor16(float x) {
  return __int_as_float(__builtin_amdgcn_ds_swizzle(__float_as_int(x), 0x401F));
}

#define YREDUCE()                                                         \
  { y += __shfl_xor(y, 32);                                               \
    y += swz_xor16(y);                                                    \
    y += dpp_movf<0x128>(y);   /* row_ror:8   */                          \
    y += dpp_movf<0x141>(y);   /* half mirror */                          \
    y += dpp_movf<0x1B>(y);    /* quad reverse*/                          \
    y += dpp_movf<0xB1>(y); }  /* quad xor1   */

// rolling poll: slot issue / oldest-retired wait / full drain
#define PISSUE(reg, src)                                                  \
  asm volatile("global_load_dwordx4 %0, %1, off sc1" : "=v"(reg) : "v"(src))
#define PWAIT3()                                                          \
  asm volatile("s_waitcnt vmcnt(3)"                                       \
               : "+v"(q0), "+v"(q1), "+v"(q2), "+v"(q3))
#define PDRAIN()                                                          \
  asm volatile("s_waitcnt vmcnt(0)"                                       \
               : "+v"(q0), "+v"(q1), "+v"(q2), "+v"(q3))

// FULL 4-dword tag check -- load-bearing (partial-commit visibility of
// coalesced wave stores means every dword's tag matters).
#define TAGBAD(q) ((((q.x ^ want) | (q.y ^ want) | (q.z ^ want) | (q.w ^ want)) & 0xFFu))
#define TAGOK(q) (TAGBAD(q) == 0u)

// unpack one 16B chunk into two f32x2 value pairs (pair b2, b2+1)
#define UNPACK2(q, b2)                                                    \
  { xv2[b2+0] = (f32x2){__uint_as_float(q.x & 0xFFFFFF00u),               \
                        __uint_as_float(q.y & 0xFFFFFF00u)};              \
    xv2[b2+1] = (f32x2){__uint_as_float(q.z & 0xFFFFFF00u),               \
                        __uint_as_float(q.w & 0xFFFFFF00u)}; }

// --- named weight registers: row r, pairs 0..7 (cols 256*(p>>1)+4l+{2(p&1),+1})
#define DECLW(r) f32x2 W##r##0, W##r##1, W##r##2, W##r##3,                \
                      W##r##4, W##r##5, W##r##6, W##r##7

#define LOADW(r) do {                                                     \
  const float* wp = w_res + (size_t)(32 * b + 8 * ww + r) * HH + 4 * l;   \
  f32x4 va = *(const f32x4*)(wp);                                         \
  f32x4 vb = *(const f32x4*)(wp + 256);                                   \
  f32x4 vc = *(const f32x4*)(wp + 512);                                   \
  f32x4 vd = *(const f32x4*)(wp + 768);                                   \
  W##r##0 = (f32x2){va.x, va.y}; W##r##1 = (f32x2){va.z, va.w};           \
  W##r##2 = (f32x2){vb.x, vb.y}; W##r##3 = (f32x2){vb.z, vb.w};           \
  W##r##4 = (f32x2){vc.x, vc.y}; W##r##5 = (f32x2){vc.z, vc.w};           \
  W##r##6 = (f32x2){vd.x, vd.y}; W##r##7 = (f32x2){vd.z, vd.w};           \
} while (0)

// jj ascending per accumulator -> identical summation order to r13-r22
#define FMAR(r) do {                                                      \
  acc2[r] = __builtin_elementwise_fma(W##r##0, xv2[0], acc2[r]);          \
  acc2[r] = __builtin_elementwise_fma(W##r##1, xv2[1], acc2[r]);          \
  acc2[r] = __builtin_elementwise_fma(W##r##2, xv2[2], acc2[r]);          \
  acc2[r] = __builtin_elementwise_fma(W##r##3, xv2[3], acc2[r]);          \
  acc2[r] = __builtin_elementwise_fma(W##r##4, xv2[4], acc2[r]);          \
  acc2[r] = __builtin_elementwise_fma(W##r##5, xv2[5], acc2[r]);          \
  acc2[r] = __builtin_elementwise_fma(W##r##6, xv2[6], acc2[r]);          \
  acc2[r] = __builtin_elementwise_fma(W##r##7, xv2[7], acc2[r]);          \
} while (0)

__global__ __launch_bounds__(NT, 1) void esn_kernel(
    const float* __restrict__ u,
    const float* __restrict__ w_in,
    const float* __restrict__ w_res,
    const float* __restrict__ w_out,
    const int*   __restrict__ mask,
    float*       __restrict__ out,
    char*        __restrict__ ws)
{
  const int tid = threadIdx.x;
  const int l  = tid & 63;     // lane within wave
  const int ww = tid >> 6;     // wave id within block (0..3) = quarter owner

  // --- team formation: XCD 0 only, first 32 claimant BLOCKS persist ---
  u32 xcc;
  asm("s_getreg_b32 %0, hwreg(HW_REG_XCC_ID)" : "=s"(xcc));
  if (xcc != 0) return;        // uniform per block (block lives on one CU)

  // PLACEMENT FORCE (r22-proven): 96 KiB static LDS -> 1 block/CU ->
  // the 32 claim winners sit on 32 distinct CUs.
  __shared__ __align__(16) char lds_all[LDSPAD];
  float* lds_c = (float*)lds_all;                        // 4 KB coeffs
  u32 (*lds_x)[HH] = (u32 (*)[HH])(lds_all + 4096);      // 2x4 KB state
  int* slot_p = (int*)(lds_all + 4096 + 8192);

  if (tid == 0) *slot_p = atomicAdd((int*)ws, 1);  // ws[0..63] zeroed each launch
  // init readout coeffs while the claim settles
  for (int h = tid; h < HH; h += NT) lds_c[mask[h]] = w_out[h];
  __syncthreads();
  const int b = *slot_p;
  if (b >= NBROLE) return;

  u32* xb0 = (u32*)(ws + 4096);        // parity-0 packed buffer (4 KB)
  u32* xb1 = xb0 + HH;                 // parity-1 packed buffer (4 KB)

  // weights: 8 rows x 8 col-pairs per lane (rows 32b+8ww .. +8)
  DECLW(0); DECLW(1); DECLW(2); DECLW(3);
  DECLW(4); DECLW(5); DECLW(6); DECLW(7);
  LOADW(0); LOADW(1); LOADW(2); LOADW(3);
  LOADW(4); LOADW(5); LOADW(6); LOADW(7);

  const float win = w_in[32 * b + 8 * ww + (l >> 3)];

  f32x2 cr2[8];                        // readout coeffs, same col map
#pragma unroll
  for (int k = 0; k < 4; ++k) {
    f32x4 v = *(const f32x4*)(lds_c + 256 * k + 4 * l);
    cr2[2*k+0] = (f32x2){v.x, v.y};
    cr2[2*k+1] = (f32x2){v.z, v.w};
  }

  // own-quarter poll pointers: wave ww covers cols [256ww, 256ww+256)
  const u32* pS0 = xb0 + 256 * ww + 4 * l;
  const u32* pS1 = xb1 + 256 * ww + 4 * l;
  // publish pointers: lane (l&7)==0 stores row 32b+8ww+(l>>3)
  const int drow = 32 * b + 8 * ww + (l >> 3);
  u32* d0 = xb0 + drow;
  u32* d1 = xb1 + drow;
  // LDS staging address (own quarter)
  const int stg = 256 * ww + 4 * l;

  const int role = (b << 2) | ww;      // 0..127, readout rotation
  u32x4 q0, q1, q2, q3, p;
  const int lb32 = l & 32, lb16 = l & 16, lb8 = l & 8;
  int dead = 0;

  for (int t = 0; t < TT; ++t) {
    const int pa = t & 1;
    const float u_t = u[t];
    f32x2 acc2[8];
#pragma unroll
    for (int i = 0; i < 8; ++i) acc2[i] = (f32x2){0.f, 0.f};
    f32x2 xv2[8];
    const bool doRead = ((t & 127) == role) && (t > 0);

    if (t > 0) {
      const int h = pa ^ 1;            // source parity = (t-1)&1
      if (!dead) {
        // delayed first issue covers publish->commit; rolling 4-deep
        // polls thereafter detect on the ~35-70cyc check period, not
        // the ~225cyc serial RTT boundary.
        __builtin_amdgcn_s_sleep(2);
        const u32* src = h ? pS1 : pS0;
        const u32 want = (u32)t & 0xFFu;   // generation of x_{t-1}
        u32 guard = 0;
        PISSUE(q0, src); PISSUE(q1, src); PISSUE(q2, src); PISSUE(q3, src);
        for (;;) {
          PWAIT3();
          if (__all(TAGOK(q0))) { p = q0; break; }
          PISSUE(q0, src);
          PWAIT3();
          if (__all(TAGOK(q1))) { p = q1; break; }
          PISSUE(q1, src);
          PWAIT3();
          if (__all(TAGOK(q2))) { p = q2; break; }
          PISSUE(q2, src);
          PWAIT3();
          if (__all(TAGOK(q3))) { p = q3; break; }
          PISSUE(q3, src);
          if ((guard += 4) > SPIN_CAP) { dead = 1; p = q3; break; }
        }
      }
      // stage own quarter to LDS; drain leftover polls; barrier; read full
      *(u32x4*)(&lds_x[h][stg]) = p;
      PDRAIN();
      __syncthreads();
      u32x4 c0 = *(const u32x4*)(&lds_x[h][  0 + 4 * l]);
      u32x4 c1 = *(const u32x4*)(&lds_x[h][256 + 4 * l]);
      u32x4 c2 = *(const u32x4*)(&lds_x[h][512 + 4 * l]);
      u32x4 c3 = *(const u32x4*)(&lds_x[h][768 + 4 * l]);
      UNPACK2(c0, 0); UNPACK2(c1, 2); UNPACK2(c2, 4); UNPACK2(c3, 6);
      // packed dual-pipe FP32: 64 v_pk_fma_f32
      FMAR(0); FMAR(1); FMAR(2); FMAR(3);
      FMAR(4); FMAR(5); FMAR(6); FMAR(7);
    }

    // horizontal pair-sum, then fold 64 lanes x 8 accs -> row (l>>3) sum
    // on lanes with (l&7)==0
    const float a0 = acc2[0].x + acc2[0].y, a1 = acc2[1].x + acc2[1].y;
    const float a2 = acc2[2].x + acc2[2].y, a3 = acc2[3].x + acc2[3].y;
    const float a4 = acc2[4].x + acc2[4].y, a5 = acc2[5].x + acc2[5].y;
    const float a6 = acc2[6].x + acc2[6].y, a7 = acc2[7].x + acc2[7].y;
    float t0 = (lb32 ? a4 : a0) + __shfl_xor(lb32 ? a0 : a4, 32);
    float t1 = (lb32 ? a5 : a1) + __shfl_xor(lb32 ? a1 : a5, 32);
    float t2 = (lb32 ? a6 : a2) + __shfl_xor(lb32 ? a2 : a6, 32);
    float t3 = (lb32 ? a7 : a3) + __shfl_xor(lb32 ? a3 : a7, 32);
    float s0 = (lb16 ? t2 : t0) + swz_xor16(lb16 ? t0 : t2);
    float s1 = (lb16 ? t3 : t1) + swz_xor16(lb16 ? t1 : t3);
    float r0 = (lb8 ? s1 : s0) + dpp_movf<0x128>(lb8 ? s0 : s1);
    r0 += dpp_movf<0x141>(r0);
    r0 += dpp_movf<0x1B>(r0);
    r0 += dpp_movf<0xB1>(r0);

    float x_new = fast_tanh(fmaf(win, u_t, r0));
    // pack: RN-round mantissa to 15 bits, fuse generation tag (t+1)&0xFF
    u32 packed = ((__float_as_uint(x_new) + 0x80u) & 0xFFFFFF00u)
               | ((u32)(t + 1) & 0xFFu);
    if ((l & 7) == 0) {
      u32* dst = pa ? d1 : d0;          // x_t -> buf[t&1]
      // PLAIN store: write-through L1 -> dirty in XCD0's shared L2
      // (r9-proven; r16 proved atomics force the exchange out of L2).
      asm volatile("global_store_dword %0, %1, off" :: "v"(dst), "v"(packed));
    }

    // readout y_{t-1} from this step's unpacked values (off critical path)
    if (doRead) {
      f32x2 y2 = (f32x2){0.f, 0.f};
#pragma unroll
      for (int jj = 0; jj < 8; ++jj)
        y2 = __builtin_elementwise_fma(cr2[jj], xv2[jj], y2);
      float y = y2.x + y2.y;
      YREDUCE();
      if (l == 0 && t - 1 >= WASH) out[t - 1 - WASH] = y;
    }
  }

  // final readout: x_{TT-1} (tag TT) in buf[1]; block 0 does one more
  // exchange (cold path -- serial poll + barrier fine here).
  if (b == 0) {
    const u32 want = (u32)TT & 0xFFu;
    u32 guard = 0;
    for (;;) {
      PISSUE(q0, pS1);
      PDRAIN();
      if (__all(TAGOK(q0))) break;
      if (++guard > SPIN_CAP) break;
    }
    p = q0;
    *(u32x4*)(&lds_x[1][stg]) = p;
    __syncthreads();
    if (ww == 0) {
      f32x2 xv2[8];
      u32x4 c0 = *(const u32x4*)(&lds_x[1][  0 + 4 * l]);
      u32x4 c1 = *(const u32x4*)(&lds_x[1][256 + 4 * l]);
      u32x4 c2 = *(const u32x4*)(&lds_x[1][512 + 4 * l]);
      u32x4 c3 = *(const u32x4*)(&lds_x[1][768 + 4 * l]);
      UNPACK2(c0, 0); UNPACK2(c1, 2); UNPACK2(c2, 4); UNPACK2(c3, 6);
      f32x2 y2 = (f32x2){0.f, 0.f};
#pragma unroll
      for (int jj = 0; jj < 8; ++jj)
        y2 = __builtin_elementwise_fma(cr2[jj], xv2[jj], y2);
      float y = y2.x + y2.y;
      YREDUCE();
      if (l == 0) out[TT - 1 - WASH] = y;
    }
  }
}

extern "C" void kernel_launch(void* const* d_in, const int* in_sizes, int n_in,
                              void* d_out, int out_size, void* d_ws, size_t ws_size,
                              hipStream_t stream) {
  const float* u     = (const float*)d_in[0];
  const float* w_in  = (const float*)d_in[1];
  const float* w_res = (const float*)d_in[2];
  const float* w_out = (const float*)d_in[3];
  const int*   mask  = (const int*)d_in[4];
  float* out = (float*)d_out;

  // zero the block-claim counter; packed buffers rely on 0xAA poison
  // (tag byte 0xAA only ever compared against want in {1,2})
  hipMemsetAsync(d_ws, 0, 64, stream);

  esn_kernel<<<NBLK, NT, 0, stream>>>(u, w_in, w_res, w_out, mask, out,
                                      (char*)d_ws);
}

// Round 13
// 42832.056 us; speedup vs baseline: 1.2699x; 1.0012x over previous
//
#include <hip/hip_runtime.h>

// Echo-state network recurrence on MI355X (gfx950).
// Round-25: BARRIER-FREE DIRECT POLL under placement force. r24 (rolling
// poll, clean placement) was null -> detection already succeeds on round
// 1-2 after sleep(2); detect ~= commit+RTT ~= 450cy, near-irreducible.
// Remaining untested-under-placement structure: the LDS exchange itself.
// The r15-vs-r12 verdict (cooperative > full-poll by 1.3ms) predates the
// placement force and is void (collision lottery), like r17's. This
// round: each wave polls the FULL 4KB itself (4x16B/lane batched = same
// RTT as 1 load), checks all 16 tags, and feeds FMAs straight from poll
// registers. Deletes: stage ds_write + __syncthreads (which couples the
// 4 waves' jitter per CU: barrier = max-of-4 every step) + 4 post-barrier
// ds_read_b128 (~120cy). Costs: 4x poll read BW (512KB/round team-wide;
// r15 showed the traffic wall is soft: 4x cut bought only -2.7%).
// Summation order identical (load k <-> pairs 2k,2k+1 == c0..c3) ->
// absmax 0.125. Placement force (96KiB LDS, r22-proven) retained; LDS
// now holds only the coeff permute + claim slot.

#define HH    1024
#define TT    50000
#define WASH  200
#define NBROLE 32   // block role b; wave ww -> global role 4b+ww, rows [8role, 8role+8)
#define NBLK  512
#define NT    256
#define SPIN_CAP (1u << 20)
#define LDSPAD 98304   // 96 KiB total LDS -> 1 block/CU (LDS pool 160 KiB)

typedef unsigned int u32;
typedef u32 u32x4 __attribute__((ext_vector_type(4)));
typedef float f32x4 __attribute__((ext_vector_type(4)));
typedef float f32x2 __attribute__((ext_vector_type(2)));

__device__ __forceinline__ float fast_tanh(float x) {
  // tanh(x) = 1 - 2/(exp2(2x*log2e)+1); safe at +/-inf.
  float e = __builtin_amdgcn_exp2f(x * 2.8853900817779268f);
  return fmaf(-2.0f, __builtin_amdgcn_rcpf(e + 1.0f), 1.0f);
}

template <int CTRL>
__device__ __forceinline__ float dpp_movf(float x) {
  return __int_as_float(__builtin_amdgcn_update_dpp(
      0, __float_as_int(x), CTRL, 0xF, 0xF, true));
}
__device__ __forceinline__ float swz_xor16(float x) {
  return __int_as_float(__builtin_amdgcn_ds_swizzle(__float_as_int(x), 0x401F));
}

#define YREDUCE()                                                         \
  { y += __shfl_xor(y, 32);                                               \
    y += swz_xor16(y);                                                    \
    y += dpp_movf<0x128>(y);   /* row_ror:8   */                          \
    y += dpp_movf<0x141>(y);   /* half mirror */                          \
    y += dpp_movf<0x1B>(y);    /* quad reverse*/                          \
    y += dpp_movf<0xB1>(y); }  /* quad xor1   */

// full-state poll: 4 batched 16B loads cover all 1024 packed elements.
// Load k, lane l -> cols {256k+4l .. +3} = pairs 2k, 2k+1 (== r22's c0..c3).
#define POLL_ISSUE4(bp)                                                               \
  asm volatile("global_load_dwordx4 %0, %1, off sc1"             : "=v"(p0) : "v"(bp)); \
  asm volatile("global_load_dwordx4 %0, %1, off offset:1024 sc1" : "=v"(p1) : "v"(bp)); \
  asm volatile("global_load_dwordx4 %0, %1, off offset:2048 sc1" : "=v"(p2) : "v"(bp)); \
  asm volatile("global_load_dwordx4 %0, %1, off offset:3072 sc1" : "=v"(p3) : "v"(bp))
#define POLL_WAIT0()                                                      \
  asm volatile("s_waitcnt vmcnt(0)"                                       \
               : "+v"(p0), "+v"(p1), "+v"(p2), "+v"(p3))

// FULL tag check, every dword (partial-commit visibility: load-bearing).
#define TAGBAD(q) ((((q.x ^ want) | (q.y ^ want) | (q.z ^ want) | (q.w ^ want)) & 0xFFu))
#define TAGBAD_ALL (TAGBAD(p0) | TAGBAD(p1) | TAGBAD(p2) | TAGBAD(p3))

// unpack one 16B chunk into two f32x2 value pairs (pair b2, b2+1)
#define UNPACK2(q, b2)                                                    \
  { xv2[b2+0] = (f32x2){__uint_as_float(q.x & 0xFFFFFF00u),               \
                        __uint_as_float(q.y & 0xFFFFFF00u)};              \
    xv2[b2+1] = (f32x2){__uint_as_float(q.z & 0xFFFFFF00u),               \
                        __uint_as_float(q.w & 0xFFFFFF00u)}; }

// --- named weight registers: row r, pairs 0..7 (cols 256*(p>>1)+4l+{2(p&1),+1})
#define DECLW(r) f32x2 W##r##0, W##r##1, W##r##2, W##r##3,                \
                      W##r##4, W##r##5, W##r##6, W##r##7

#define LOADW(r) do {                                                     \
  const float* wp = w_res + (size_t)(32 * b + 8 * ww + r) * HH + 4 * l;   \
  f32x4 va = *(const f32x4*)(wp);                                         \
  f32x4 vb = *(const f32x4*)(wp + 256);                                   \
  f32x4 vc = *(const f32x4*)(wp + 512);                                   \
  f32x4 vd = *(const f32x4*)(wp + 768);                                   \
  W##r##0 = (f32x2){va.x, va.y}; W##r##1 = (f32x2){va.z, va.w};           \
  W##r##2 = (f32x2){vb.x, vb.y}; W##r##3 = (f32x2){vb.z, vb.w};           \
  W##r##4 = (f32x2){vc.x, vc.y}; W##r##5 = (f32x2){vc.z, vc.w};           \
  W##r##6 = (f32x2){vd.x, vd.y}; W##r##7 = (f32x2){vd.z, vd.w};           \
} while (0)

// jj ascending per accumulator -> identical summation order to r13-r24
#define FMAR(r) do {                                                      \
  acc2[r] = __builtin_elementwise_fma(W##r##0, xv2[0], acc2[r]);          \
  acc2[r] = __builtin_elementwise_fma(W##r##1, xv2[1], acc2[r]);          \
  acc2[r] = __builtin_elementwise_fma(W##r##2, xv2[2], acc2[r]);          \
  acc2[r] = __builtin_elementwise_fma(W##r##3, xv2[3], acc2[r]);          \
  acc2[r] = __builtin_elementwise_fma(W##r##4, xv2[4], acc2[r]);          \
  acc2[r] = __builtin_elementwise_fma(W##r##5, xv2[5], acc2[r]);          \
  acc2[r] = __builtin_elementwise_fma(W##r##6, xv2[6], acc2[r]);          \
  acc2[r] = __builtin_elementwise_fma(W##r##7, xv2[7], acc2[r]);          \
} while (0)

__global__ __launch_bounds__(NT, 1) void esn_kernel(
    const float* __restrict__ u,
    const float* __restrict__ w_in,
    const float* __restrict__ w_res,
    const float* __restrict__ w_out,
    const int*   __restrict__ mask,
    float*       __restrict__ out,
    char*        __restrict__ ws)
{
  const int tid = threadIdx.x;
  const int l  = tid & 63;     // lane within wave
  const int ww = tid >> 6;     // wave id within block (0..3)

  // --- team formation: XCD 0 only, first 32 claimant BLOCKS persist ---
  u32 xcc;
  asm("s_getreg_b32 %0, hwreg(HW_REG_XCC_ID)" : "=s"(xcc));
  if (xcc != 0) return;        // uniform per block (block lives on one CU)

  // PLACEMENT FORCE (r22-proven): 96 KiB static LDS -> 1 block/CU ->
  // the 32 claim winners sit on 32 distinct CUs. LDS otherwise holds
  // only the permuted coeffs + claim slot (no state exchange this round).
  __shared__ __align__(16) char lds_all[LDSPAD];
  float* lds_c = (float*)lds_all;                        // 4 KB coeffs
  int* slot_p = (int*)(lds_all + 4096);

  if (tid == 0) *slot_p = atomicAdd((int*)ws, 1);  // ws[0..63] zeroed each launch
  // init readout coeffs while the claim settles
  for (int h = tid; h < HH; h += NT) lds_c[mask[h]] = w_out[h];
  __syncthreads();
  const int b = *slot_p;
  if (b >= NBROLE) return;

  u32* xb0 = (u32*)(ws + 4096);        // parity-0 packed buffer (4 KB)
  u32* xb1 = xb0 + HH;                 // parity-1 packed buffer (4 KB)

  // weights: 8 rows x 8 col-pairs per lane (rows 32b+8ww .. +8)
  DECLW(0); DECLW(1); DECLW(2); DECLW(3);
  DECLW(4); DECLW(5); DECLW(6); DECLW(7);
  LOADW(0); LOADW(1); LOADW(2); LOADW(3);
  LOADW(4); LOADW(5); LOADW(6); LOADW(7);

  const float win = w_in[32 * b + 8 * ww + (l >> 3)];

  f32x2 cr2[8];                        // readout coeffs, same col map
#pragma unroll
  for (int k = 0; k < 4; ++k) {
    f32x4 v = *(const f32x4*)(lds_c + 256 * k + 4 * l);
    cr2[2*k+0] = (f32x2){v.x, v.y};
    cr2[2*k+1] = (f32x2){v.z, v.w};
  }

  // full-state poll pointers (per lane: 4 chunks at +0/+1024/+2048/+3072 B)
  const u32* pA0 = xb0 + 4 * l;
  const u32* pA1 = xb1 + 4 * l;
  // publish pointers: lane (l&7)==0 stores row 32b+8ww+(l>>3)
  const int drow = 32 * b + 8 * ww + (l >> 3);
  u32* d0 = xb0 + drow;
  u32* d1 = xb1 + drow;

  const int role = (b << 2) | ww;      // 0..127, readout rotation
  u32x4 p0, p1, p2, p3;
  const int lb32 = l & 32, lb16 = l & 16, lb8 = l & 8;
  int dead = 0;

  for (int t = 0; t < TT; ++t) {
    const int pa = t & 1;
    const float u_t = u[t];
    f32x2 acc2[8];
#pragma unroll
    for (int i = 0; i < 8; ++i) acc2[i] = (f32x2){0.f, 0.f};
    f32x2 xv2[8];
    const bool doRead = ((t & 127) == role) && (t > 0);

    if (t > 0) {
      if (!dead) {
        // delayed first poll: publish->ready >= store-commit + RTT;
        // sleep(2)=128cy is hidden slack that kills the guaranteed-failed
        // first round (r13/r24-consistent: detection lands on round 1-2).
        __builtin_amdgcn_s_sleep(2);
        const u32* src = pa ? pA0 : pA1;   // source = buf[(t-1)&1]
        const u32 want = (u32)t & 0xFFu;   // generation of x_{t-1}
        u32 guard = 0;
        for (;;) {
          POLL_ISSUE4(src);
          POLL_WAIT0();
          if (!TAGBAD_ALL) break;
          if (++guard > SPIN_CAP) { dead = 1; break; }
        }
      }
      // feed FMAs straight from poll registers -- no stage, no barrier,
      // no ds_read. Pair map identical to r22's c0..c3.
      UNPACK2(p0, 0); UNPACK2(p1, 2); UNPACK2(p2, 4); UNPACK2(p3, 6);
      FMAR(0); FMAR(1); FMAR(2); FMAR(3);
      FMAR(4); FMAR(5); FMAR(6); FMAR(7);
    }

    // horizontal pair-sum, then fold 64 lanes x 8 accs -> row (l>>3) sum
    // on lanes with (l&7)==0
    const float a0 = acc2[0].x + acc2[0].y, a1 = acc2[1].x + acc2[1].y;
    const float a2 = acc2[2].x + acc2[2].y, a3 = acc2[3].x + acc2[3].y;
    const float a4 = acc2[4].x + acc2[4].y, a5 = acc2[5].x + acc2[5].y;
    const float a6 = acc2[6].x + acc2[6].y, a7 = acc2[7].x + acc2[7].y;
    float t0 = (lb32 ? a4 : a0) + __shfl_xor(lb32 ? a0 : a4, 32);
    float t1 = (lb32 ? a5 : a1) + __shfl_xor(lb32 ? a1 : a5, 32);
    float t2 = (lb32 ? a6 : a2) + __shfl_xor(lb32 ? a2 : a6, 32);
    float t3 = (lb32 ? a7 : a3) + __shfl_xor(lb32 ? a3 : a7, 32);
    float s0 = (lb16 ? t2 : t0) + swz_xor16(lb16 ? t0 : t2);
    float s1 = (lb16 ? t3 : t1) + swz_xor16(lb16 ? t1 : t3);
    float r0 = (lb8 ? s1 : s0) + dpp_movf<0x128>(lb8 ? s0 : s1);
    r0 += dpp_movf<0x141>(r0);
    r0 += dpp_movf<0x1B>(r0);
    r0 += dpp_movf<0xB1>(r0);

    float x_new = fast_tanh(fmaf(win, u_t, r0));
    // pack: RN-round mantissa to 15 bits, fuse generation tag (t+1)&0xFF
    u32 packed = ((__float_as_uint(x_new) + 0x80u) & 0xFFFFFF00u)
               | ((u32)(t + 1) & 0xFFu);
    if ((l & 7) == 0) {
      u32* dst = pa ? d1 : d0;          // x_t -> buf[t&1]
      // PLAIN store: write-through L1 -> dirty in XCD0's shared L2
      // (r9-proven; r16 proved atomics force the exchange out of L2).
      asm volatile("global_store_dword %0, %1, off" :: "v"(dst), "v"(packed));
    }

    // readout y_{t-1} from this step's unpacked values (off critical path)
    if (doRead) {
      f32x2 y2 = (f32x2){0.f, 0.f};
#pragma unroll
      for (int jj = 0; jj < 8; ++jj)
        y2 = __builtin_elementwise_fma(cr2[jj], xv2[jj], y2);
      float y = y2.x + y2.y;
      YREDUCE();
      if (l == 0 && t - 1 >= WASH) out[t - 1 - WASH] = y;
    }
  }

  // final readout: x_{TT-1} (tag TT) in buf[1]; role 0 polls directly.
  if (b == 0 && ww == 0) {
    const u32 want = (u32)TT & 0xFFu;
    u32 guard = 0;
    for (;;) {
      POLL_ISSUE4(pA1);
      POLL_WAIT0();
      if (!TAGBAD_ALL) break;
      if (++guard > SPIN_CAP) break;
    }
    f32x2 xv2[8];
    UNPACK2(p0, 0); UNPACK2(p1, 2); UNPACK2(p2, 4); UNPACK2(p3, 6);
    f32x2 y2 = (f32x2){0.f, 0.f};
#pragma unroll
    for (int jj = 0; jj < 8; ++jj)
      y2 = __builtin_elementwise_fma(cr2[jj], xv2[jj], y2);
    float y = y2.x + y2.y;
    YREDUCE();
    if (l == 0) out[TT - 1 - WASH] = y;
  }
}

extern "C" void kernel_launch(void* const* d_in, const int* in_sizes, int n_in,
                              void* d_out, int out_size, void* d_ws, size_t ws_size,
                              hipStream_t stream) {
  const float* u     = (const float*)d_in[0];
  const float* w_in  = (const float*)d_in[1];
  const float* w_res = (const float*)d_in[2];
  const float* w_out = (const float*)d_in[3];
  const int*   mask  = (const int*)d_in[4];
  float* out = (float*)d_out;

  // zero the block-claim counter; packed buffers rely on 0xAA poison
  // (tag byte 0xAA only ever compared against want in {1,2})
  hipMemsetAsync(d_ws, 0, 64, stream);

  esn_kernel<<<NBLK, NT, 0, stream>>>(u, w_in, w_res, w_out, mask, out,
                                      (char*)d_ws);
}